// Round 13
// baseline (1511.245 us; speedup 1.0000x reference)
//
#include <hip/hip_runtime.h>
#include <math.h>

#define BATCH 2
#define NN 50000
#define NE 400000
#define C_IN 5
#define CC 128
#define SS 32
#define NH 8
#define NL 4
#define FFN 512
#define COORD_F 8
#define TIME_F 4
#define HD 16
#define BETA 1.0f
#define TWO_PI 6.283185307179586476925287f

#define NTOT (BATCH * NN)
#define FF_MT 128
#define FF_BLOCKS ((NTOT + FF_MT - 1) / FF_MT)   // 782 (buffer sizing)
#define MPAD (FF_BLOCKS * FF_MT)                  // 100096
#define NBLK ((NN + 127) / 128)                   // 391 per-batch blocks
#define LP_PAD 136                                // u16 row pad (272B, 16B-aligned)
#define H2S 136                                   // ffn_mega h2t/stage stride (u16)
#define HIDS 72                                   // ffn_mega hid stride (u16)
#define NREP 16                                   // slices_acc replicas
#define EMB_NPB 8                                 // embed nodes per block
#define PROJ_NPB 12                               // proj nodes per block

typedef unsigned short u16;
typedef unsigned int u32;
typedef __attribute__((ext_vector_type(8))) __bf16 bf16x8;
typedef __attribute__((ext_vector_type(4))) float f32x4;

// hardware RNE convert (v_cvt_pk_bf16_f32) — bit-identical to manual round-to-nearest-even
__device__ __forceinline__ u16 f2bf(float f) {
    union { __bf16 b; u16 u; } v;
    v.b = (__bf16)f;
    return v.u;
}

__device__ __forceinline__ float bf2f(u16 h) {
    union { u32 u; float f; } v; v.u = ((u32)h) << 16;
    return v.f;
}

__device__ __forceinline__ float bf_lo(u32 u) {
    union { u32 u; float f; } v; v.u = u << 16;
    return v.f;
}

__device__ __forceinline__ float bf_hi(u32 u) {
    union { u32 u; float f; } v; v.u = u & 0xffff0000u;
    return v.f;
}

// erf via Abramowitz-Stegun 7.1.26 (max abs err 1.5e-7)
__device__ __forceinline__ float gelu_f(float a) {
    float xx = a * 0.7071067811865475f;
    float ax = fabsf(xx);
    float t = 1.0f / fmaf(0.3275911f, ax, 1.0f);
    float poly = t * fmaf(t, fmaf(t, fmaf(t, fmaf(t, 1.061405429f, -1.453152027f),
                                          1.421413741f), -0.284496736f), 0.254829592f);
    float e = __expf(-ax * ax);
    float erfv = copysignf(fmaf(-poly, e, 1.0f), xx);
    return 0.5f * a * (1.0f + erfv);
}

// ---------------- CSR build ----------------
__global__ void count_deg(const int* rows, int* deg) {
    int e = blockIdx.x * blockDim.x + threadIdx.x;
    if (e < NE) atomicAdd(&deg[rows[e]], 1);
}

__global__ __launch_bounds__(512) void scan_deg(const int* deg, int* rowptr) {
    __shared__ int part[512];
    int t = threadIdx.x;
    const int CH = (NN + 511) / 512;  // 98
    int begin = t * CH, end = min(begin + CH, NN);
    int s = 0;
    for (int i = begin; i < end; i++) s += deg[i];
    part[t] = s;
    __syncthreads();
    for (int off = 1; off < 512; off <<= 1) {
        int v = (t >= off) ? part[t - off] : 0;
        __syncthreads();
        part[t] += v;
        __syncthreads();
    }
    int base = (t == 0) ? 0 : part[t - 1];
    for (int i = begin; i < end; i++) { rowptr[i] = base; base += deg[i]; }
    if (t == 511) rowptr[NN] = part[511];
}

__global__ void fill_csr(const int* rows, const int* cols, const float* vals,
                         int* cursor, int* csr_col, float* csr_val) {
    int e = blockIdx.x * blockDim.x + threadIdx.x;
    if (e < NE) {
        int p = atomicAdd(&cursor[rows[e]], 1);
        csr_col[p] = cols[e];
        csr_val[p] = vals[e];
    }
}

// ---------------- embed + LN1 fused ----------------
__global__ __launch_bounds__(128) void embed_ln1_kernel(const float* __restrict__ inputs,
                                                        const float* __restrict__ coords,
                                                        const float* __restrict__ t_norm,
                                                        const float* __restrict__ freq,
                                                        const float* __restrict__ W,
                                                        const float* __restrict__ bias,
                                                        const float* __restrict__ g,
                                                        const float* __restrict__ bb,
                                                        float* __restrict__ x,
                                                        u16* __restrict__ hbf) {
    int t = threadIdx.x;
    int n0 = blockIdx.x * EMB_NPB;
    __shared__ float feat[EMB_NPB][32];
    __shared__ float sm[EMB_NPB][4];
    if (t < EMB_NPB) {
        int node = n0 + t;
        if (node < NTOT) {
            int b = node / NN;
            float c0 = coords[node * 2 + 0], c1 = coords[node * 2 + 1];
            #pragma unroll
            for (int j = 0; j < 8; j++) {
                float p = TWO_PI * (c0 * freq[j] + c1 * freq[8 + j]);
                feat[t][5 + j] = sinf(p);
                feat[t][13 + j] = cosf(p);
            }
            #pragma unroll
            for (int j = 0; j < 4; j++) {
                float omega = powf(1000.0f, -(float)j * 0.25f);
                float ang = omega * t_norm[b] * 1000.0f;
                feat[t][21 + j] = sinf(ang);
                feat[t][25 + j] = cosf(ang);
            }
            #pragma unroll
            for (int k = 0; k < 5; k++) feat[t][k] = inputs[node * 5 + k];
        }
    }
    float Wr[29];
    #pragma unroll
    for (int k = 0; k < 29; k++) Wr[k] = W[k * CC + t];
    float bi = bias[t], gt = g[t], bbt = bb[t];
    __syncthreads();
    float accv[EMB_NPB];
    #pragma unroll
    for (int nn = 0; nn < EMB_NPB; nn++) {
        float a = bi;
        #pragma unroll
        for (int k = 0; k < 29; k++) a += feat[nn][k] * Wr[k];
        accv[nn] = a;
        int node = n0 + nn;
        if (node < NTOT) x[(size_t)node * CC + t] = a;
    }
    #pragma unroll
    for (int nn = 0; nn < EMB_NPB; nn++) {
        float s = accv[nn];
        #pragma unroll
        for (int off = 32; off > 0; off >>= 1) s += __shfl_xor(s, off, 64);
        if ((t & 63) == 0) sm[nn][t >> 6] = s;
    }
    __syncthreads();
    float dv[EMB_NPB];
    #pragma unroll
    for (int nn = 0; nn < EMB_NPB; nn++) {
        float mean = (sm[nn][0] + sm[nn][1]) * (1.0f / 128.0f);
        float d = accv[nn] - mean;
        dv[nn] = d;
        float ss = d * d;
        #pragma unroll
        for (int off = 32; off > 0; off >>= 1) ss += __shfl_xor(ss, off, 64);
        if ((t & 63) == 0) sm[nn][2 + (t >> 6)] = ss;
    }
    __syncthreads();
    #pragma unroll
    for (int nn = 0; nn < EMB_NPB; nn++) {
        int node = n0 + nn;
        if (node < NTOT) {
            float var = (sm[nn][2] + sm[nn][3]) * (1.0f / 128.0f);
            hbf[(size_t)node * CC + t] = f2bf(dv[nn] * rsqrtf(var + 1e-5f) * gt + bbt);
        }
    }
}

// ---------------- sparse aggregation (gather via CSR, bf16 in/out) ----------------
// one WAVE per node; lane loads u32 = 2 channels; 8-edge unroll (8 gathers in flight).
__global__ __launch_bounds__(256) void agg_kernel(const u16* __restrict__ hbf,
                                                  const int* __restrict__ rowptr,
                                                  const int* __restrict__ csr_col,
                                                  const float* __restrict__ csr_val,
                                                  u16* __restrict__ hlbf) {
    int wid = threadIdx.x >> 6;
    int lane = threadIdx.x & 63;
    int node = blockIdx.x * 4 + wid;      // 0..NTOT (NTOT % 4 == 0)
    int b = node / NN, r = node - b * NN;
    int s0 = rowptr[r], s1 = rowptr[r + 1];
    const u32* hb = (const u32*)(hbf + (size_t)b * NN * CC);
    float a0l = 0.f, a1l = 0.f, a2l = 0.f, a3l = 0.f;
    float a0h = 0.f, a1h = 0.f, a2h = 0.f, a3h = 0.f;
    int e = s0;
    for (; e + 8 <= s1; e += 8) {
        int c0 = csr_col[e],     c1 = csr_col[e + 1], c2 = csr_col[e + 2], c3 = csr_col[e + 3];
        int c4 = csr_col[e + 4], c5 = csr_col[e + 5], c6 = csr_col[e + 6], c7 = csr_col[e + 7];
        float v0 = csr_val[e],     v1 = csr_val[e + 1], v2 = csr_val[e + 2], v3 = csr_val[e + 3];
        float v4 = csr_val[e + 4], v5 = csr_val[e + 5], v6 = csr_val[e + 6], v7 = csr_val[e + 7];
        u32 u0 = hb[(size_t)c0 * 64 + lane];
        u32 u1 = hb[(size_t)c1 * 64 + lane];
        u32 u2 = hb[(size_t)c2 * 64 + lane];
        u32 u3 = hb[(size_t)c3 * 64 + lane];
        u32 u4 = hb[(size_t)c4 * 64 + lane];
        u32 u5 = hb[(size_t)c5 * 64 + lane];
        u32 u6 = hb[(size_t)c6 * 64 + lane];
        u32 u7 = hb[(size_t)c7 * 64 + lane];
        a0l += v0 * bf_lo(u0);  a0h += v0 * bf_hi(u0);
        a1l += v1 * bf_lo(u1);  a1h += v1 * bf_hi(u1);
        a2l += v2 * bf_lo(u2);  a2h += v2 * bf_hi(u2);
        a3l += v3 * bf_lo(u3);  a3h += v3 * bf_hi(u3);
        a0l += v4 * bf_lo(u4);  a0h += v4 * bf_hi(u4);
        a1l += v5 * bf_lo(u5);  a1h += v5 * bf_hi(u5);
        a2l += v6 * bf_lo(u6);  a2h += v6 * bf_hi(u6);
        a3l += v7 * bf_lo(u7);  a3h += v7 * bf_hi(u7);
    }
    for (; e + 4 <= s1; e += 4) {
        int c0 = csr_col[e], c1 = csr_col[e + 1], c2 = csr_col[e + 2], c3 = csr_col[e + 3];
        float v0 = csr_val[e], v1 = csr_val[e + 1], v2 = csr_val[e + 2], v3 = csr_val[e + 3];
        u32 u0 = hb[(size_t)c0 * 64 + lane];
        u32 u1 = hb[(size_t)c1 * 64 + lane];
        u32 u2 = hb[(size_t)c2 * 64 + lane];
        u32 u3 = hb[(size_t)c3 * 64 + lane];
        a0l += v0 * bf_lo(u0);  a0h += v0 * bf_hi(u0);
        a1l += v1 * bf_lo(u1);  a1h += v1 * bf_hi(u1);
        a2l += v2 * bf_lo(u2);  a2h += v2 * bf_hi(u2);
        a3l += v3 * bf_lo(u3);  a3h += v3 * bf_hi(u3);
    }
    for (; e < s1; e++) {
        float v = csr_val[e];
        u32 u = hb[(size_t)csr_col[e] * 64 + lane];
        a0l += v * bf_lo(u);  a0h += v * bf_hi(u);
    }
    float al = (a0l + a1l) + (a2l + a3l);
    float ah = (a0h + a1h) + (a2h + a3h);
    u32 outv = (u32)f2bf(al) | ((u32)f2bf(ah) << 16);
    ((u32*)hlbf)[(size_t)node * 64 + lane] = outv;
}

// ---------------- pack combined logits weights ----------------
__global__ __launch_bounds__(256) void pack_logits_weights(const float* Ws, const float* bs,
                                                           const float* Wf, const float* bf,
                                                           u16* Wcombp, float* bcombp) {
    int idx = blockIdx.x * 256 + threadIdx.x;
    if (idx >= NL * SS * 256) return;
    int l = idx / (SS * 256);
    int r = idx - l * (SS * 256);
    int s = r >> 8, k = r & 255;
    float v;
    if (k < 128)
        v = Ws[(size_t)l * CC * SS + (size_t)k * SS + s] + BETA * Wf[(size_t)l * CC * SS + (size_t)k * SS + s];
    else
        v = -BETA * Wf[(size_t)l * CC * SS + (size_t)(k - 128) * SS + s];
    Wcombp[idx] = f2bf(v);
    if (k == 0) bcombp[l * SS + s] = bs[l * SS + s] + BETA * bf[l * SS + s];
}

// ---------------- fused logits + softmax + slice pooling ----------------
// grid (NBLK, BATCH); 256 thr = 4 waves; 128 nodes/block; each wave owns 32 nodes.
// Pooling partitioned by OUTPUT COLUMNS (wave wv owns cols [wv*32,wv*32+32), full K)
// -> complete per-wave accumulators, no cross-wave LDS reduce (R12: -248 us total).
__global__ __launch_bounds__(256, 2) void logits_pool(const u16* __restrict__ hbf,
                                                      const u16* __restrict__ hlbf,
                                                      const u16* __restrict__ Wcomb,
                                                      const float* __restrict__ bcomb,
                                                      float* __restrict__ wout,
                                                      float* __restrict__ rep,
                                                      float* __restrict__ wsum) {
    __shared__ __align__(16) u16 hT[128 * LP_PAD];   // [c][n_local]
    __shared__ __align__(16) u16 wTh[SS * LP_PAD];   // [s][n_local] hi
    __shared__ __align__(16) u16 wTl[SS * LP_PAD];   // lo
    __shared__ float wsum_sh[SS];
    int t = threadIdx.x;
    int b = blockIdx.y;
    int nl0 = blockIdx.x * 128;                      // local node base (within batch)
    int wv = t >> 6, lane = t & 63;
    int q = lane >> 4, ln16 = lane & 15;
    int nl0w = nl0 + wv * 32;                        // this wave's 32-node base
    if (t < SS) wsum_sh[t] = 0.0f;
    __syncthreads();

    // ---- logits GEMM + hT transpose ----
    f32x4 acc[2][2];
    #pragma unroll
    for (int mi = 0; mi < 2; mi++)
        #pragma unroll
        for (int ni = 0; ni < 2; ni++) acc[mi][ni] = (f32x4){0.f, 0.f, 0.f, 0.f};

    #pragma unroll
    for (int ks = 0; ks < 8; ks++) {
        const u16* src = (ks < 4) ? hbf : hlbf;
        int ko = (ks & 3) * 32 + q * 8;
        bf16x8 af[2], bfrg[2];
        #pragma unroll
        for (int mi = 0; mi < 2; mi++) {
            int nl = nl0w + mi * 16 + ln16;          // local node of this A row
            af[mi] = *(const bf16x8*)&src[((size_t)b * NN + nl) * CC + ko];
            if (ks < 4) {
                bool valid = nl < NN;
                const u16* ap = (const u16*)&af[mi];
                int nlb = nl - nl0;                  // 0..127 within block
                #pragma unroll
                for (int i = 0; i < 8; i++)
                    hT[(ko + i) * LP_PAD + nlb] = valid ? ap[i] : (u16)0;
            }
        }
        #pragma unroll
        for (int ni = 0; ni < 2; ni++)
            bfrg[ni] = *(const bf16x8*)&Wcomb[(size_t)(ni * 16 + ln16) * 256 + ks * 32 + q * 8];
        #pragma unroll
        for (int mi = 0; mi < 2; mi++)
            #pragma unroll
            for (int ni = 0; ni < 2; ni++)
                acc[mi][ni] = __builtin_amdgcn_mfma_f32_16x16x32_bf16(af[mi], bfrg[ni], acc[mi][ni], 0, 0, 0);
    }

    // ---- in-register softmax + w output + wT tiles + wsum ----
    float bc0 = bcomb[ln16], bc1 = bcomb[16 + ln16];
    float ws0 = 0.0f, ws1 = 0.0f;
    #pragma unroll
    for (int mi = 0; mi < 2; mi++)
        #pragma unroll
        for (int r = 0; r < 4; r++) {
            float l0 = acc[mi][0][r] + bc0;
            float l1 = acc[mi][1][r] + bc1;
            float m = fmaxf(l0, l1);
            #pragma unroll
            for (int msk = 1; msk < 16; msk <<= 1) m = fmaxf(m, __shfl_xor(m, msk, 64));
            float e0 = __expf(l0 - m), e1 = __expf(l1 - m);
            float sum = e0 + e1;
            #pragma unroll
            for (int msk = 1; msk < 16; msk <<= 1) sum += __shfl_xor(sum, msk, 64);
            float is = 1.0f / sum;
            int nl = nl0w + mi * 16 + q * 4 + r;     // local node (row)
            bool valid = nl < NN;
            float w0 = valid ? e0 * is : 0.0f;
            float w1 = valid ? e1 * is : 0.0f;
            u16 h0 = f2bf(w0), h1 = f2bf(w1);
            u16 lo0 = f2bf(w0 - bf2f(h0)), lo1 = f2bf(w1 - bf2f(h1));
            if (valid) {
                size_t gb = ((size_t)b * NN + nl) * SS;
                wout[gb + ln16] = w0;
                wout[gb + 16 + ln16] = w1;
            }
            int nlb = nl - nl0;
            wTh[ln16 * LP_PAD + nlb] = h0;  wTl[ln16 * LP_PAD + nlb] = lo0;
            wTh[(16 + ln16) * LP_PAD + nlb] = h1;  wTl[(16 + ln16) * LP_PAD + nlb] = lo1;
            ws0 += w0;  ws1 += w1;
        }
    // reduce wsum partials across q groups (lanes with same ln16)
    ws0 += __shfl_xor(ws0, 16, 64); ws0 += __shfl_xor(ws0, 32, 64);
    ws1 += __shfl_xor(ws1, 16, 64); ws1 += __shfl_xor(ws1, 32, 64);
    if (q == 0) {
        atomicAdd(&wsum_sh[ln16], ws0);
        atomicAdd(&wsum_sh[16 + ln16], ws1);
    }
    __syncthreads();   // wT/hT writes + wsum_sh atomics complete

    // ---- pooling MFMA: wave wv owns cols [wv*32, wv*32+32); full K sequentially ----
    f32x4 pacc[2][2];
    #pragma unroll
    for (int st = 0; st < 2; st++)
        #pragma unroll
        for (int ctl = 0; ctl < 2; ctl++) pacc[st][ctl] = (f32x4){0.f, 0.f, 0.f, 0.f};
    #pragma unroll
    for (int ks = 0; ks < 4; ks++) {
        int kb = ks * 32 + q * 8;
        bf16x8 wh[2], wl2[2], bfr[2];
        #pragma unroll
        for (int st = 0; st < 2; st++) {
            wh[st] = *(const bf16x8*)&wTh[(st * 16 + ln16) * LP_PAD + kb];
            wl2[st] = *(const bf16x8*)&wTl[(st * 16 + ln16) * LP_PAD + kb];
        }
        #pragma unroll
        for (int ctl = 0; ctl < 2; ctl++)
            bfr[ctl] = *(const bf16x8*)&hT[((wv * 2 + ctl) * 16 + ln16) * LP_PAD + kb];
        #pragma unroll
        for (int ctl = 0; ctl < 2; ctl++)
            #pragma unroll
            for (int st = 0; st < 2; st++) {
                pacc[st][ctl] = __builtin_amdgcn_mfma_f32_16x16x32_bf16(wh[st], bfr[ctl], pacc[st][ctl], 0, 0, 0);
                pacc[st][ctl] = __builtin_amdgcn_mfma_f32_16x16x32_bf16(wl2[st], bfr[ctl], pacc[st][ctl], 0, 0, 0);
            }
    }

    // ---- direct replica atomics (no cross-wave reduce needed) ----
    if (t < SS) atomicAdd(&wsum[b * SS + t], wsum_sh[t]);
    int rep_id = (blockIdx.y * NBLK + blockIdx.x) & (NREP - 1);
    float* dst = rep + ((size_t)rep_id * BATCH + b) * SS * CC;
    #pragma unroll
    for (int st = 0; st < 2; st++)
        #pragma unroll
        for (int ctl = 0; ctl < 2; ctl++)
            #pragma unroll
            for (int r = 0; r < 4; r++)
                atomicAdd(&dst[(st * 16 + q * 4 + r) * CC + (wv * 2 + ctl) * 16 + ln16],
                          pacc[st][ctl][r]);
}

// ---------------- slice MHA, stage 1: qkv = (replica-sum/wsum) @ Win + b_in ----------------
// replica reduction fused in (same r=0..15 summation order as reduce_slices); grid=64.
__global__ __launch_bounds__(128) void qkv_kernel(const float* __restrict__ rep,
                                                  const float* wsum,
                                                  const float* Win, const float* b_in_p,
                                                  float* qkv) {
    int blk = blockIdx.x;  // b*SS + s
    int b = blk >> 5;
    int t = threadIdx.x;
    __shared__ float row[128];
    int e = (blk & 31) * CC + t;          // s*CC + c within batch b
    float s = 0.0f;
    #pragma unroll
    for (int r = 0; r < NREP; r++) s += rep[((size_t)r * BATCH + b) * SS * CC + e];
    float iv = 1.0f / fmaxf(wsum[blk], 1e-8f);
    row[t] = s * iv;
    __syncthreads();
    #pragma unroll
    for (int jj = 0; jj < 3; jj++) {
        int j = t + jj * 128;
        float a = b_in_p[j];
        #pragma unroll 8
        for (int c = 0; c < 128; c++) a += row[c] * Win[c * 384 + j];
        qkv[(size_t)blk * 384 + j] = a;
    }
}

// ---------------- fused attention + out-projection ----------------
// R13: replaces attn_kernel + mha_out_kernel (one launch less, no ovals round-trip).
// grid = B*SS (64 blocks), 128 thr. Threads t<8 each run the EXACT serial per-head
// attention body (same k-ascending max/exp/accum order, same inputs -> bit-identical
// o values); o staged in LDS; then all 128 threads run the exact mha_out dot
// (cc-ascending) reading LDS instead of the old ovals global buffer.
__global__ __launch_bounds__(128) void attn_out_kernel(const float* __restrict__ qkv,
                                                       const float* __restrict__ Wout,
                                                       const float* __restrict__ bout,
                                                       u16* __restrict__ soThi,
                                                       u16* __restrict__ soTlo) {
    int blk = blockIdx.x;  // b*SS + s
    int b = blk >> 5, s = blk & 31;
    int t = threadIdx.x;
    __shared__ float ksh[NH * 32 * 16];   // [h][k][d] 16 KB
    __shared__ float vsh[NH * 32 * 16];   // 16 KB
    __shared__ float osh[128];            // o row for this s
    for (int i = t; i < NH * 32 * 16; i += 128) {
        int h = i >> 9, k = (i >> 4) & 31, d = i & 15;
        ksh[i] = qkv[((size_t)b * 32 + k) * 384 + 128 + h * 16 + d];
        vsh[i] = qkv[((size_t)b * 32 + k) * 384 + 256 + h * 16 + d];
    }
    __syncthreads();
    if (t < NH) {
        int h = t;
        const float* kh = &ksh[h * 512];
        const float* vh = &vsh[h * 512];
        float qr[16];
        #pragma unroll
        for (int d = 0; d < 16; d++) qr[d] = qkv[((size_t)b * 32 + s) * 384 + h * 16 + d];
        float sc[32];
        float m = -1e30f;
        for (int k = 0; k < 32; k++) {
            float a = 0.0f;
            #pragma unroll
            for (int d = 0; d < 16; d++) a += qr[d] * kh[k * 16 + d];
            a *= 0.25f;  // 1/sqrt(16)
            sc[k] = a;
            m = fmaxf(m, a);
        }
        float ssum = 0.0f;
        for (int k = 0; k < 32; k++) { float e = expf(sc[k] - m); sc[k] = e; ssum += e; }
        float is = 1.0f / ssum;
        float o[16];
        #pragma unroll
        for (int d = 0; d < 16; d++) o[d] = 0.0f;
        for (int k = 0; k < 32; k++) {
            float p = sc[k] * is;
            #pragma unroll
            for (int d = 0; d < 16; d++) o[d] += p * vh[k * 16 + d];
        }
        #pragma unroll
        for (int d = 0; d < 16; d++) osh[h * 16 + d] = o[d];
    }
    __syncthreads();
    // out-projection: t = output col c (exact mha_out arithmetic, LDS-sourced row)
    float a = bout[t];
    #pragma unroll 8
    for (int cc = 0; cc < 128; cc++) a += osh[cc] * Wout[cc * CC + t];
    u16 hi = f2bf(a);
    size_t idx = (size_t)b * CC * SS + (size_t)t * SS + s;
    soThi[idx] = hi;
    soTlo[idx] = f2bf(a - bf2f(hi));
}

// ---------------- pack FFN weights to bf16 fragment-friendly layouts ----------------
__global__ __launch_bounds__(256) void pack_ffn_weights(const float* Wff1, const float* Wff2,
                                                        u16* W1p, u16* W2p) {
    int idx = blockIdx.x * 256 + threadIdx.x;
    if (idx >= NL * FFN * CC) return;
    int l = idx / (FFN * CC);
    int r = idx - l * (FFN * CC);
    int j = r >> 7, c = r & 127;          // W1p flat index [l][j][c]
    W1p[idx] = f2bf(Wff1[(size_t)l * CC * FFN + (size_t)c * FFN + j]);
    int c2 = r >> 9, j2 = r & 511;        // W2p flat index [l][c2][j2]
    W2p[idx] = f2bf(Wff2[(size_t)l * FFN * CC + (size_t)j2 * CC + c2]);
}

// ---------------- mega kernel: broadcast + residual + LN2 + FFN + next-layer LN1 ----------------
// R4 structure (verified 148.5 us), FROZEN except phase 0's w source: loads fp32 wout
// (same 32 B/fragment as the old whi+wlo pair) and recomputes hi=f2bf(w),
// lo=f2bf(w-bf2f(hi)) in registers — bit-identical MFMA inputs.
__global__ __launch_bounds__(256, 2) void ffn_mega(float* __restrict__ x,
                                                   const float* __restrict__ wfull,
                                                   const u16* __restrict__ soThi,
                                                   const u16* __restrict__ soTlo,
                                                   const float* __restrict__ g,
                                                   const float* __restrict__ bb,
                                                   const u16* __restrict__ W1p,
                                                   const float* __restrict__ bff1,
                                                   const u16* __restrict__ W2p,
                                                   const float* __restrict__ bff2,
                                                   const float* __restrict__ g1,
                                                   const float* __restrict__ b1,
                                                   u16* __restrict__ hbf_out) {
    __shared__ __align__(16) u16 smem[128 * 144];   // 36864 B: h2t(s136) -> hid dbuf(2x s72) -> stage(s136)
    __shared__ __align__(16) float rowst[128 * 4];  // 2048 B LN stats
    u16* h2t = smem;
    int t = threadIdx.x;
    int b = blockIdx.y;
    int n0 = blockIdx.x * 128;
    int wave = t >> 6, lane = t & 63;
    int wm = wave >> 1, wn = wave & 1;
    int q = lane >> 4, ln16 = lane & 15;
    bool emit = (g1 != nullptr);

    // per-thread LN2 params (cols fixed per thread)
    float gr[4], br[4];
    #pragma unroll
    for (int ni = 0; ni < 4; ni++) {
        int col = wn * 64 + ni * 16 + ln16;
        gr[ni] = g[col]; br[ni] = bb[col];
    }

    f32x4 acc2[4][4];
    #pragma unroll
    for (int mi = 0; mi < 4; mi++)
        #pragma unroll
        for (int ni = 0; ni < 4; ni++) acc2[mi][ni] = (f32x4){0.f, 0.f, 0.f, 0.f};

    // ---- phase 0: acc2 = w@so via 3-pass hi/lo MFMA (hi/lo recomputed from fp32 w) ----
    {
        const u16* soh = soThi + (size_t)b * CC * SS;
        const u16* sol = soTlo + (size_t)b * CC * SS;
        bf16x8 bh[4], bl[4], ah[4], al[4];
        bf16x8 zf;
        #pragma unroll
        for (int i = 0; i < 8; i++) zf[i] = (__bf16)0.0f;
        #pragma unroll
        for (int ni = 0; ni < 4; ni++) {
            int c = wn * 64 + ni * 16 + ln16;
            bh[ni] = *(const bf16x8*)&soh[c * SS + q * 8];
            bl[ni] = *(const bf16x8*)&sol[c * SS + q * 8];
        }
        #pragma unroll
        for (int mi = 0; mi < 4; mi++) {
            int row = n0 + wm * 64 + mi * 16 + ln16;
            if (row < NN) {
                const float* wp = &wfull[((size_t)b * NN + row) * SS + q * 8];
                f32x4 wv0 = *(const f32x4*)wp;
                f32x4 wv1 = *(const f32x4*)(wp + 4);
                union { bf16x8 v; u16 u[8]; } uh, ul;
                #pragma unroll
                for (int i = 0; i < 4; i++) {
                    u16 h = f2bf(wv0[i]);
                    uh.u[i] = h;  ul.u[i] = f2bf(wv0[i] - bf2f(h));
                }
                #pragma unroll
                for (int i = 0; i < 4; i++) {
                    u16 h = f2bf(wv1[i]);
                    uh.u[4 + i] = h;  ul.u[4 + i] = f2bf(wv1[i] - bf2f(h));
                }
                ah[mi] = uh.v;  al[mi] = ul.v;
            } else { ah[mi] = zf; al[mi] = zf; }
        }
        #pragma unroll
        for (int mi = 0; mi < 4; mi++)
            #pragma unroll
            for (int ni = 0; ni < 4; ni++) {
                acc2[mi][ni] = __builtin_amdgcn_mfma_f32_16x16x32_bf16(ah[mi], bh[ni], acc2[mi][ni], 0, 0, 0);
                acc2[mi][ni] = __builtin_amdgcn_mfma_f32_16x16x32_bf16(al[mi], bh[ni], acc2[mi][ni], 0, 0, 0);
                acc2[mi][ni] = __builtin_amdgcn_mfma_f32_16x16x32_bf16(ah[mi], bl[ni], acc2[mi][ni], 0, 0, 0);
            }
    }

    // ---- phase 1: acc2 += x (residual); LN2 stats; h2 -> LDS (stride H2S) ----
    #pragma unroll
    for (int mi = 0; mi < 4; mi++)
        #pragma unroll
        for (int r = 0; r < 4; r++) {
            int row = n0 + wm * 64 + mi * 16 + q * 4 + r;
            if (row < NN) {
                const float* xr = &x[((size_t)b * NN + row) * CC + wn * 64 + ln16];
                #pragma unroll
                for (int ni = 0; ni < 4; ni++) acc2[mi][ni][r] += xr[ni * 16];
            }
        }
    #pragma unroll
    for (int mi = 0; mi < 4; mi++)
        #pragma unroll
        for (int r = 0; r < 4; r++) {
            float a = acc2[mi][0][r] + acc2[mi][1][r] + acc2[mi][2][r] + acc2[mi][3][r];
            float a2 = acc2[mi][0][r] * acc2[mi][0][r] + acc2[mi][1][r] * acc2[mi][1][r] +
                       acc2[mi][2][r] * acc2[mi][2][r] + acc2[mi][3][r] * acc2[mi][3][r];
            #pragma unroll
            for (int msk = 1; msk < 16; msk <<= 1) {
                a += __shfl_xor(a, msk, 64);
                a2 += __shfl_xor(a2, msk, 64);
            }
            if (ln16 == 0) {
                int m = wm * 64 + mi * 16 + q * 4 + r;
                rowst[m * 4 + wn * 2] = a;
                rowst[m * 4 + wn * 2 + 1] = a2;
            }
        }
    __syncthreads();
    #pragma unroll
    for (int mi = 0; mi < 4; mi++)
        #pragma unroll
        for (int r = 0; r < 4; r++) {
            int m = wm * 64 + mi * 16 + q * 4 + r;
            float s1 = rowst[m * 4 + 0] + rowst[m * 4 + 2];
            float s2 = rowst[m * 4 + 1] + rowst[m * 4 + 3];
            float mean = s1 * (1.0f / 128.0f);
            float var = s2 * (1.0f / 128.0f) - mean * mean;
            float rstd = rsqrtf(fmaxf(var, 0.0f) + 1e-5f);
            #pragma unroll
            for (int ni = 0; ni < 4; ni++) {
                int col = wn * 64 + ni * 16 + ln16;
                h2t[m * H2S + col] = f2bf((acc2[mi][ni][r] - mean) * rstd * gr[ni] + br[ni]);
            }
        }
    __syncthreads();

    // ---- phase 1.5: pull this wave's GEMM1 A-fragments into registers (frees smem) ----
    bf16x8 areg[4][4];   // [ks][mi]
    #pragma unroll
    for (int ks = 0; ks < 4; ks++)
        #pragma unroll
        for (int mi = 0; mi < 4; mi++)
            areg[ks][mi] = *(const bf16x8*)&h2t[(wm * 64 + mi * 16 + ln16) * H2S + ks * 32 + q * 8];
    __syncthreads();   // all h2t reads done; smem becomes hid double-buffer

    // ---- phase 2: FFN; ONE barrier per jc; acc2 (holding x+broadcast) accumulates GEMM2 ----
    for (int jc = 0; jc < 8; jc++) {
        u16* hid = smem + (jc & 1) * (128 * HIDS);
        f32x4 acc1[4][2];
        #pragma unroll
        for (int mi = 0; mi < 4; mi++)
            #pragma unroll
            for (int ni = 0; ni < 2; ni++) acc1[mi][ni] = (f32x4){0.f, 0.f, 0.f, 0.f};

        __builtin_amdgcn_s_setprio(1);
        #pragma unroll
        for (int ks = 0; ks < 4; ks++) {
            bf16x8 bfr[2];
            #pragma unroll
            for (int ni = 0; ni < 2; ni++)
                bfr[ni] = *(const bf16x8*)&W1p[(size_t)(jc * 64 + wn * 32 + ni * 16 + ln16) * CC + ks * 32 + q * 8];
            #pragma unroll
            for (int mi = 0; mi < 4; mi++)
                #pragma unroll
                for (int ni = 0; ni < 2; ni++)
                    acc1[mi][ni] = __builtin_amdgcn_mfma_f32_16x16x32_bf16(areg[ks][mi], bfr[ni], acc1[mi][ni], 0, 0, 0);
        }
        __builtin_amdgcn_s_setprio(0);

        #pragma unroll
        for (int ni = 0; ni < 2; ni++) {
            float b1v = bff1[jc * 64 + wn * 32 + ni * 16 + ln16];
            #pragma unroll
            for (int mi = 0; mi < 4; mi++)
                #pragma unroll
                for (int r = 0; r < 4; r++)
                    hid[(wm * 64 + mi * 16 + q * 4 + r) * HIDS + wn * 32 + ni * 16 + ln16] =
                        f2bf(gelu_f(acc1[mi][ni][r] + b1v));
        }
        __syncthreads();   // hid[jc&1] complete; next jc writes the other buffer

        __builtin_amdgcn_s_setprio(1);
        #pragma unroll
        for (int ks2 = 0; ks2 < 2; ks2++) {
            bf16x8 af[4], bfr[4];
            #pragma unroll
            for (int mi = 0; mi < 4; mi++)
                af[mi] = *(const bf16x8*)&hid[(wm * 64 + mi * 16 + ln16) * HIDS + ks2 * 32 + q * 8];
            #pragma unroll
            for (int ni = 0; ni < 4; ni++)
                bfr[ni] = *(const bf16x8*)&W2p[(size_t)(wn * 64 + ni * 16 + ln16) * FFN + jc * 64 + ks2 * 32 + q * 8];
            #pragma unroll
            for (int mi = 0; mi < 4; mi++)
                #pragma unroll
                for (int ni = 0; ni < 4; ni++)
                    acc2[mi][ni] = __builtin_amdgcn_mfma_f32_16x16x32_bf16(af[mi], bfr[ni], acc2[mi][ni], 0, 0, 0);
        }
        __builtin_amdgcn_s_setprio(0);
    }

    // ---- epilogue: fold bff2; store x; optional next-layer LN1 -> hbf (staged, coalesced) ----
    float b2[4];
    #pragma unroll
    for (int ni = 0; ni < 4; ni++) b2[ni] = bff2[wn * 64 + ni * 16 + ln16];
    #pragma unroll
    for (int mi = 0; mi < 4; mi++)
        #pragma unroll
        for (int ni = 0; ni < 4; ni++)
            #pragma unroll
            for (int r = 0; r < 4; r++) acc2[mi][ni][r] += b2[ni];

    #pragma unroll
    for (int mi = 0; mi < 4; mi++)
        #pragma unroll
        for (int r = 0; r < 4; r++) {
            int row = n0 + wm * 64 + mi * 16 + q * 4 + r;
            if (row < NN) {
                float* xo = &x[((size_t)b * NN + row) * CC + wn * 64 + ln16];
                #pragma unroll
                for (int ni = 0; ni < 4; ni++) xo[ni * 16] = acc2[mi][ni][r];
            }
        }

    if (emit) {
        float g1r[4], b1r[4];
        #pragma unroll
        for (int ni = 0; ni < 4; ni++) {
            int col = wn * 64 + ni * 16 + ln16;
            g1r[ni] = g1[col]; b1r[ni] = b1[col];
        }
        #pragma unroll
        for (int mi = 0; mi < 4; mi++)
            #pragma unroll
            for (int r = 0; r < 4; r++) {
                float a = acc2[mi][0][r] + acc2[mi][1][r] + acc2[mi][2][r] + acc2[mi][3][r];
                float a2 = acc2[mi][0][r] * acc2[mi][0][r] + acc2[mi][1][r] * acc2[mi][1][r] +
                           acc2[mi][2][r] * acc2[mi][2][r] + acc2[mi][3][r] * acc2[mi][3][r];
                #pragma unroll
                for (int msk = 1; msk < 16; msk <<= 1) {
                    a += __shfl_xor(a, msk, 64);
                    a2 += __shfl_xor(a2, msk, 64);
                }
                if (ln16 == 0) {
                    int m = wm * 64 + mi * 16 + q * 4 + r;
                    rowst[m * 4 + wn * 2] = a;
                    rowst[m * 4 + wn * 2 + 1] = a2;
                }
            }
        __syncthreads();   // rowst visible AND all jc-loop hid reads drained -> smem reusable
        #pragma unroll
        for (int mi = 0; mi < 4; mi++)
            #pragma unroll
            for (int r = 0; r < 4; r++) {
                int m = wm * 64 + mi * 16 + q * 4 + r;
                float s1 = rowst[m * 4 + 0] + rowst[m * 4 + 2];
                float s2 = rowst[m * 4 + 1] + rowst[m * 4 + 3];
                float mean = s1 * (1.0f / 128.0f);
                float var = s2 * (1.0f / 128.0f) - mean * mean;
                float rstd = rsqrtf(fmaxf(var, 0.0f) + 1e-5f);
                #pragma unroll
                for (int ni = 0; ni < 4; ni++) {
                    int col = wn * 64 + ni * 16 + ln16;
                    smem[m * H2S + col] = f2bf((acc2[mi][ni][r] - mean) * rstd * g1r[ni] + b1r[ni]);
                }
            }
        __syncthreads();
        // coalesced 16B-chunk copy LDS -> hbf_out
        #pragma unroll
        for (int it = 0; it < 8; it++) {
            int chunk = it * 256 + t;            // 2048 chunks = 128 rows x 16 chunks
            int m = chunk >> 4;
            int c8 = (chunk & 15) << 3;
            int row = n0 + m;
            if (row < NN)
                *(f32x4*)&hbf_out[((size_t)b * NN + row) * CC + c8] =
                    *(const f32x4*)&smem[m * H2S + c8];
        }
    }
}

// ---------------- final projection ----------------
__global__ __launch_bounds__(128) void proj_kernel(const float* __restrict__ x,
                                                   const float* __restrict__ W,
                                                   const float* __restrict__ bias,
                                                   float* __restrict__ outp) {
    int t = threadIdx.x;
    int n0 = blockIdx.x * PROJ_NPB;
    __shared__ float xr[PROJ_NPB][128];
    __shared__ float pr[3][40];
    for (int idx = t; idx < PROJ_NPB * 128; idx += 128) {
        int nn = idx >> 7, c = idx & 127;
        int node = n0 + nn;
        xr[nn][c] = (node < NTOT) ? x[(size_t)node * CC + c] : 0.0f;
    }
    __syncthreads();
    for (int pass = 0; pass < 4; pass++) {
        if (t < 120) {
            int nl = t / 40, tt = t - nl * 40;
            int k = tt / 8, part = tt % 8;
            float a = 0.0f;
            #pragma unroll
            for (int i = 0; i < 16; i++) {
                int c = part * 16 + i;
                a += xr[pass * 3 + nl][c] * W[c * C_IN + k];
            }
            pr[nl][tt] = a;
        }
        __syncthreads();
        if (t < 15) {
            int nl = t / 5, k = t - nl * 5;
            int node = n0 + pass * 3 + nl;
            if (node < NTOT) {
                float a = bias[k];
                #pragma unroll
                for (int p = 0; p < 8; p++) a += pr[nl][k * 8 + p];
                outp[(size_t)node * C_IN + k] = a;
            }
        }
        __syncthreads();
    }
}

extern "C" void kernel_launch(void* const* d_in, const int* in_sizes, int n_in,
                              void* d_out, int out_size, void* d_ws, size_t ws_size,
                              hipStream_t stream) {
    const float* inputs  = (const float*)d_in[0];
    const float* coords  = (const float*)d_in[1];
    const float* t_norm  = (const float*)d_in[2];
    const int*   adj     = (const int*)d_in[3];
    const float* adj_v   = (const float*)d_in[4];
    const float* freq    = (const float*)d_in[5];
    const float* embed_W = (const float*)d_in[6];
    const float* embed_b = (const float*)d_in[7];
    const float* ln1_g   = (const float*)d_in[8];
    const float* ln1_b   = (const float*)d_in[9];
    const float* Wslice  = (const float*)d_in[10];
    const float* bslice  = (const float*)d_in[11];
    const float* Wfront  = (const float*)d_in[12];
    const float* bfront  = (const float*)d_in[13];
    const float* Win     = (const float*)d_in[14];
    const float* b_in    = (const float*)d_in[15];
    const float* Wout    = (const float*)d_in[16];
    const float* bout    = (const float*)d_in[17];
    const float* ln2_g   = (const float*)d_in[18];
    const float* ln2_b   = (const float*)d_in[19];
    const float* Wff1    = (const float*)d_in[20];
    const float* bff1    = (const float*)d_in[21];
    const float* Wff2    = (const float*)d_in[22];
    const float* bff2    = (const float*)d_in[23];
    const float* proj_W  = (const float*)d_in[24];
    const float* proj_b  = (const float*)d_in[25];

    float* out = (float*)d_out;
    float* wout_base = out + (size_t)BATCH * NN * C_IN;

    // workspace layout
    float* x          = (float*)d_ws;
    u16*   hbf        = (u16*)(x + (size_t)NTOT * CC);
    u16*   hlbf       = hbf + (size_t)MPAD * CC;
    u16*   soThi      = hlbf + (size_t)MPAD * CC;            // BATCH*CC*SS
    u16*   soTlo      = soThi + BATCH * CC * SS;
    float* qkv_ws     = (float*)(soTlo + BATCH * CC * SS);   // BATCH*SS*384
    float* csr_val    = qkv_ws + BATCH * SS * 384;
    int*   rowptr     = (int*)(csr_val + NE);
    int*   cursor     = rowptr + (NN + 1);
    int*   deg        = cursor + NN;
    int*   csr_col    = deg + NN;
    u16*   W1p        = (u16*)(csr_col + NE);       // NL*FFN*CC bf16
    u16*   W2p        = W1p + NL * FFN * CC;        // NL*CC*FFN bf16
    u16*   Wcombp     = W2p + NL * CC * FFN;        // NL*SS*256 bf16
    float* bcomb      = (float*)(Wcombp + NL * SS * 256);  // NL*SS fp32
    float* rep        = bcomb + NL * SS;            // NREP*BATCH*SS*CC fp32 (512 KB)
    float* wsum       = rep + (size_t)NREP * BATCH * SS * CC;  // BATCH*SS, adjacent for 1 memset

    // ---- CSR build ----
    hipMemsetAsync(deg, 0, NN * sizeof(int), stream);
    count_deg<<<(NE + 255) / 256, 256, 0, stream>>>(adj, deg);
    scan_deg<<<1, 512, 0, stream>>>(deg, rowptr);
    hipMemcpyAsync(cursor, rowptr, NN * sizeof(int), hipMemcpyDeviceToDevice, stream);
    fill_csr<<<(NE + 255) / 256, 256, 0, stream>>>(adj, adj + NE, adj_v, cursor, csr_col, csr_val);

    // ---- pack weights (bf16) ----
    pack_ffn_weights<<<(NL * FFN * CC + 255) / 256, 256, 0, stream>>>(Wff1, Wff2, W1p, W2p);
    pack_logits_weights<<<(NL * SS * 256 + 255) / 256, 256, 0, stream>>>(Wslice, bslice, Wfront,
                                                                         bfront, Wcombp, bcomb);

    // ---- embed + LN1(layer 0) ----
    embed_ln1_kernel<<<(NTOT + EMB_NPB - 1) / EMB_NPB, 128, 0, stream>>>(
        inputs, coords, t_norm, freq, embed_W, embed_b, ln1_g, ln1_b, x, hbf);

    for (int l = 0; l < NL; l++) {
        float* wl = wout_base + (size_t)l * NTOT * SS;
        agg_kernel<<<NTOT / 4, 256, 0, stream>>>(hbf, rowptr, csr_col, csr_val, hlbf);
        hipMemsetAsync(rep, 0, ((size_t)NREP * BATCH * SS * CC + BATCH * SS) * sizeof(float), stream);
        dim3 glp(NBLK, BATCH);
        logits_pool<<<glp, 256, 0, stream>>>(hbf, hlbf, Wcombp + (size_t)l * SS * 256,
                                             bcomb + l * SS, wl, rep, wsum);
        // MHA (2-stage: qkv, then fused attn+out)
        qkv_kernel<<<BATCH * SS, 128, 0, stream>>>(rep, wsum,
                                                   Win + (size_t)l * CC * 3 * CC,
                                                   b_in + l * 3 * CC, qkv_ws);
        attn_out_kernel<<<BATCH * SS, 128, 0, stream>>>(qkv_ws, Wout + (size_t)l * CC * CC,
                                                        bout + l * CC, soThi, soTlo);
        // fused broadcast + LN2 + FFN + next-layer LN1 (R4 structure; w from wout fp32)
        const float* g1n = (l + 1 < NL) ? (ln1_g + (size_t)(l + 1) * CC) : nullptr;
        const float* b1n = (l + 1 < NL) ? (ln1_b + (size_t)(l + 1) * CC) : nullptr;
        dim3 g3(NBLK, BATCH);
        ffn_mega<<<g3, 256, 0, stream>>>(x, wl, soThi, soTlo,
                                         ln2_g + l * CC, ln2_b + l * CC,
                                         W1p + (size_t)l * FFN * CC, bff1 + l * FFN,
                                         W2p + (size_t)l * CC * FFN, bff2 + l * CC,
                                         g1n, b1n, hbf);
    }

    proj_kernel<<<(NTOT + PROJ_NPB - 1) / PROJ_NPB, 128, 0, stream>>>(x, proj_W, proj_b, out);
}

// Round 14
// 1455.896 us; speedup vs baseline: 1.0380x; 1.0380x over previous
//
#include <hip/hip_runtime.h>
#include <math.h>

#define BATCH 2
#define NN 50000
#define NE 400000
#define C_IN 5
#define CC 128
#define SS 32
#define NH 8
#define NL 4
#define FFN 512
#define COORD_F 8
#define TIME_F 4
#define HD 16
#define BETA 1.0f
#define TWO_PI 6.283185307179586476925287f

#define NTOT (BATCH * NN)
#define FF_MT 128
#define FF_BLOCKS ((NTOT + FF_MT - 1) / FF_MT)   // 782 (buffer sizing)
#define MPAD (FF_BLOCKS * FF_MT)                  // 100096
#define NBLK ((NN + 127) / 128)                   // 391 per-batch blocks
#define LP_PAD 136                                // u16 row pad (272B, 16B-aligned)
#define H2S 136                                   // ffn_mega h2t/stage stride (u16)
#define HIDS 72                                   // ffn_mega hid stride (u16)
#define NREP 16                                   // slices_acc replicas
#define EMB_NPB 8                                 // embed nodes per block
#define PROJ_NPB 12                               // proj nodes per block

typedef unsigned short u16;
typedef unsigned int u32;
typedef __attribute__((ext_vector_type(8))) __bf16 bf16x8;
typedef __attribute__((ext_vector_type(4))) float f32x4;

// hardware RNE convert (v_cvt_pk_bf16_f32) — bit-identical to manual round-to-nearest-even
__device__ __forceinline__ u16 f2bf(float f) {
    union { __bf16 b; u16 u; } v;
    v.b = (__bf16)f;
    return v.u;
}

__device__ __forceinline__ float bf2f(u16 h) {
    union { u32 u; float f; } v; v.u = ((u32)h) << 16;
    return v.f;
}

__device__ __forceinline__ float bf_lo(u32 u) {
    union { u32 u; float f; } v; v.u = u << 16;
    return v.f;
}

__device__ __forceinline__ float bf_hi(u32 u) {
    union { u32 u; float f; } v; v.u = u & 0xffff0000u;
    return v.f;
}

// erf via Abramowitz-Stegun 7.1.26 (max abs err 1.5e-7)
__device__ __forceinline__ float gelu_f(float a) {
    float xx = a * 0.7071067811865475f;
    float ax = fabsf(xx);
    float t = 1.0f / fmaf(0.3275911f, ax, 1.0f);
    float poly = t * fmaf(t, fmaf(t, fmaf(t, fmaf(t, 1.061405429f, -1.453152027f),
                                          1.421413741f), -0.284496736f), 0.254829592f);
    float e = __expf(-ax * ax);
    float erfv = copysignf(fmaf(-poly, e, 1.0f), xx);
    return 0.5f * a * (1.0f + erfv);
}

// ---------------- CSR build ----------------
__global__ void count_deg(const int* rows, int* deg) {
    int e = blockIdx.x * blockDim.x + threadIdx.x;
    if (e < NE) atomicAdd(&deg[rows[e]], 1);
}

__global__ __launch_bounds__(512) void scan_deg(const int* deg, int* rowptr) {
    __shared__ int part[512];
    int t = threadIdx.x;
    const int CH = (NN + 511) / 512;  // 98
    int begin = t * CH, end = min(begin + CH, NN);
    int s = 0;
    for (int i = begin; i < end; i++) s += deg[i];
    part[t] = s;
    __syncthreads();
    for (int off = 1; off < 512; off <<= 1) {
        int v = (t >= off) ? part[t - off] : 0;
        __syncthreads();
        part[t] += v;
        __syncthreads();
    }
    int base = (t == 0) ? 0 : part[t - 1];
    for (int i = begin; i < end; i++) { rowptr[i] = base; base += deg[i]; }
    if (t == 511) rowptr[NN] = part[511];
}

__global__ void fill_csr(const int* rows, const int* cols, const float* vals,
                         int* cursor, int* csr_col, float* csr_val) {
    int e = blockIdx.x * blockDim.x + threadIdx.x;
    if (e < NE) {
        int p = atomicAdd(&cursor[rows[e]], 1);
        csr_col[p] = cols[e];
        csr_val[p] = vals[e];
    }
}

// ---------------- embed + LN1 fused ----------------
__global__ __launch_bounds__(128) void embed_ln1_kernel(const float* __restrict__ inputs,
                                                        const float* __restrict__ coords,
                                                        const float* __restrict__ t_norm,
                                                        const float* __restrict__ freq,
                                                        const float* __restrict__ W,
                                                        const float* __restrict__ bias,
                                                        const float* __restrict__ g,
                                                        const float* __restrict__ bb,
                                                        float* __restrict__ x,
                                                        u16* __restrict__ hbf) {
    int t = threadIdx.x;
    int n0 = blockIdx.x * EMB_NPB;
    __shared__ float feat[EMB_NPB][32];
    __shared__ float sm[EMB_NPB][4];
    if (t < EMB_NPB) {
        int node = n0 + t;
        if (node < NTOT) {
            int b = node / NN;
            float c0 = coords[node * 2 + 0], c1 = coords[node * 2 + 1];
            #pragma unroll
            for (int j = 0; j < 8; j++) {
                float p = TWO_PI * (c0 * freq[j] + c1 * freq[8 + j]);
                feat[t][5 + j] = sinf(p);
                feat[t][13 + j] = cosf(p);
            }
            #pragma unroll
            for (int j = 0; j < 4; j++) {
                float omega = powf(1000.0f, -(float)j * 0.25f);
                float ang = omega * t_norm[b] * 1000.0f;
                feat[t][21 + j] = sinf(ang);
                feat[t][25 + j] = cosf(ang);
            }
            #pragma unroll
            for (int k = 0; k < 5; k++) feat[t][k] = inputs[node * 5 + k];
        }
    }
    float Wr[29];
    #pragma unroll
    for (int k = 0; k < 29; k++) Wr[k] = W[k * CC + t];
    float bi = bias[t], gt = g[t], bbt = bb[t];
    __syncthreads();
    float accv[EMB_NPB];
    #pragma unroll
    for (int nn = 0; nn < EMB_NPB; nn++) {
        float a = bi;
        #pragma unroll
        for (int k = 0; k < 29; k++) a += feat[nn][k] * Wr[k];
        accv[nn] = a;
        int node = n0 + nn;
        if (node < NTOT) x[(size_t)node * CC + t] = a;
    }
    #pragma unroll
    for (int nn = 0; nn < EMB_NPB; nn++) {
        float s = accv[nn];
        #pragma unroll
        for (int off = 32; off > 0; off >>= 1) s += __shfl_xor(s, off, 64);
        if ((t & 63) == 0) sm[nn][t >> 6] = s;
    }
    __syncthreads();
    float dv[EMB_NPB];
    #pragma unroll
    for (int nn = 0; nn < EMB_NPB; nn++) {
        float mean = (sm[nn][0] + sm[nn][1]) * (1.0f / 128.0f);
        float d = accv[nn] - mean;
        dv[nn] = d;
        float ss = d * d;
        #pragma unroll
        for (int off = 32; off > 0; off >>= 1) ss += __shfl_xor(ss, off, 64);
        if ((t & 63) == 0) sm[nn][2 + (t >> 6)] = ss;
    }
    __syncthreads();
    #pragma unroll
    for (int nn = 0; nn < EMB_NPB; nn++) {
        int node = n0 + nn;
        if (node < NTOT) {
            float var = (sm[nn][2] + sm[nn][3]) * (1.0f / 128.0f);
            hbf[(size_t)node * CC + t] = f2bf(dv[nn] * rsqrtf(var + 1e-5f) * gt + bbt);
        }
    }
}

// ---------------- sparse aggregation (gather via CSR, bf16 in/out) ----------------
// one WAVE per node; lane loads u32 = 2 channels; 8-edge unroll (8 gathers in flight).
__global__ __launch_bounds__(256) void agg_kernel(const u16* __restrict__ hbf,
                                                  const int* __restrict__ rowptr,
                                                  const int* __restrict__ csr_col,
                                                  const float* __restrict__ csr_val,
                                                  u16* __restrict__ hlbf) {
    int wid = threadIdx.x >> 6;
    int lane = threadIdx.x & 63;
    int node = blockIdx.x * 4 + wid;      // 0..NTOT (NTOT % 4 == 0)
    int b = node / NN, r = node - b * NN;
    int s0 = rowptr[r], s1 = rowptr[r + 1];
    const u32* hb = (const u32*)(hbf + (size_t)b * NN * CC);
    float a0l = 0.f, a1l = 0.f, a2l = 0.f, a3l = 0.f;
    float a0h = 0.f, a1h = 0.f, a2h = 0.f, a3h = 0.f;
    int e = s0;
    for (; e + 8 <= s1; e += 8) {
        int c0 = csr_col[e],     c1 = csr_col[e + 1], c2 = csr_col[e + 2], c3 = csr_col[e + 3];
        int c4 = csr_col[e + 4], c5 = csr_col[e + 5], c6 = csr_col[e + 6], c7 = csr_col[e + 7];
        float v0 = csr_val[e],     v1 = csr_val[e + 1], v2 = csr_val[e + 2], v3 = csr_val[e + 3];
        float v4 = csr_val[e + 4], v5 = csr_val[e + 5], v6 = csr_val[e + 6], v7 = csr_val[e + 7];
        u32 u0 = hb[(size_t)c0 * 64 + lane];
        u32 u1 = hb[(size_t)c1 * 64 + lane];
        u32 u2 = hb[(size_t)c2 * 64 + lane];
        u32 u3 = hb[(size_t)c3 * 64 + lane];
        u32 u4 = hb[(size_t)c4 * 64 + lane];
        u32 u5 = hb[(size_t)c5 * 64 + lane];
        u32 u6 = hb[(size_t)c6 * 64 + lane];
        u32 u7 = hb[(size_t)c7 * 64 + lane];
        a0l += v0 * bf_lo(u0);  a0h += v0 * bf_hi(u0);
        a1l += v1 * bf_lo(u1);  a1h += v1 * bf_hi(u1);
        a2l += v2 * bf_lo(u2);  a2h += v2 * bf_hi(u2);
        a3l += v3 * bf_lo(u3);  a3h += v3 * bf_hi(u3);
        a0l += v4 * bf_lo(u4);  a0h += v4 * bf_hi(u4);
        a1l += v5 * bf_lo(u5);  a1h += v5 * bf_hi(u5);
        a2l += v6 * bf_lo(u6);  a2h += v6 * bf_hi(u6);
        a3l += v7 * bf_lo(u7);  a3h += v7 * bf_hi(u7);
    }
    for (; e + 4 <= s1; e += 4) {
        int c0 = csr_col[e], c1 = csr_col[e + 1], c2 = csr_col[e + 2], c3 = csr_col[e + 3];
        float v0 = csr_val[e], v1 = csr_val[e + 1], v2 = csr_val[e + 2], v3 = csr_val[e + 3];
        u32 u0 = hb[(size_t)c0 * 64 + lane];
        u32 u1 = hb[(size_t)c1 * 64 + lane];
        u32 u2 = hb[(size_t)c2 * 64 + lane];
        u32 u3 = hb[(size_t)c3 * 64 + lane];
        a0l += v0 * bf_lo(u0);  a0h += v0 * bf_hi(u0);
        a1l += v1 * bf_lo(u1);  a1h += v1 * bf_hi(u1);
        a2l += v2 * bf_lo(u2);  a2h += v2 * bf_hi(u2);
        a3l += v3 * bf_lo(u3);  a3h += v3 * bf_hi(u3);
    }
    for (; e < s1; e++) {
        float v = csr_val[e];
        u32 u = hb[(size_t)csr_col[e] * 64 + lane];
        a0l += v * bf_lo(u);  a0h += v * bf_hi(u);
    }
    float al = (a0l + a1l) + (a2l + a3l);
    float ah = (a0h + a1h) + (a2h + a3h);
    u32 outv = (u32)f2bf(al) | ((u32)f2bf(ah) << 16);
    ((u32*)hlbf)[(size_t)node * 64 + lane] = outv;
}

// ---------------- pack combined logits weights ----------------
__global__ __launch_bounds__(256) void pack_logits_weights(const float* Ws, const float* bs,
                                                           const float* Wf, const float* bf,
                                                           u16* Wcombp, float* bcombp) {
    int idx = blockIdx.x * 256 + threadIdx.x;
    if (idx >= NL * SS * 256) return;
    int l = idx / (SS * 256);
    int r = idx - l * (SS * 256);
    int s = r >> 8, k = r & 255;
    float v;
    if (k < 128)
        v = Ws[(size_t)l * CC * SS + (size_t)k * SS + s] + BETA * Wf[(size_t)l * CC * SS + (size_t)k * SS + s];
    else
        v = -BETA * Wf[(size_t)l * CC * SS + (size_t)(k - 128) * SS + s];
    Wcombp[idx] = f2bf(v);
    if (k == 0) bcombp[l * SS + s] = bs[l * SS + s] + BETA * bf[l * SS + s];
}

// ---------------- fused logits + softmax + slice pooling ----------------
// grid (NBLK, BATCH); 256 thr = 4 waves; 128 nodes/block; each wave owns 32 nodes.
// Pooling partitioned by OUTPUT COLUMNS (wave wv owns cols [wv*32,wv*32+32), full K)
// -> complete per-wave accumulators, no cross-wave LDS reduce (R12: -248 us total).
__global__ __launch_bounds__(256, 2) void logits_pool(const u16* __restrict__ hbf,
                                                      const u16* __restrict__ hlbf,
                                                      const u16* __restrict__ Wcomb,
                                                      const float* __restrict__ bcomb,
                                                      float* __restrict__ wout,
                                                      float* __restrict__ rep,
                                                      float* __restrict__ wsum) {
    __shared__ __align__(16) u16 hT[128 * LP_PAD];   // [c][n_local]
    __shared__ __align__(16) u16 wTh[SS * LP_PAD];   // [s][n_local] hi
    __shared__ __align__(16) u16 wTl[SS * LP_PAD];   // lo
    __shared__ float wsum_sh[SS];
    int t = threadIdx.x;
    int b = blockIdx.y;
    int nl0 = blockIdx.x * 128;                      // local node base (within batch)
    int wv = t >> 6, lane = t & 63;
    int q = lane >> 4, ln16 = lane & 15;
    int nl0w = nl0 + wv * 32;                        // this wave's 32-node base
    if (t < SS) wsum_sh[t] = 0.0f;
    __syncthreads();

    // ---- logits GEMM + hT transpose ----
    f32x4 acc[2][2];
    #pragma unroll
    for (int mi = 0; mi < 2; mi++)
        #pragma unroll
        for (int ni = 0; ni < 2; ni++) acc[mi][ni] = (f32x4){0.f, 0.f, 0.f, 0.f};

    #pragma unroll
    for (int ks = 0; ks < 8; ks++) {
        const u16* src = (ks < 4) ? hbf : hlbf;
        int ko = (ks & 3) * 32 + q * 8;
        bf16x8 af[2], bfrg[2];
        #pragma unroll
        for (int mi = 0; mi < 2; mi++) {
            int nl = nl0w + mi * 16 + ln16;          // local node of this A row
            af[mi] = *(const bf16x8*)&src[((size_t)b * NN + nl) * CC + ko];
            if (ks < 4) {
                bool valid = nl < NN;
                const u16* ap = (const u16*)&af[mi];
                int nlb = nl - nl0;                  // 0..127 within block
                #pragma unroll
                for (int i = 0; i < 8; i++)
                    hT[(ko + i) * LP_PAD + nlb] = valid ? ap[i] : (u16)0;
            }
        }
        #pragma unroll
        for (int ni = 0; ni < 2; ni++)
            bfrg[ni] = *(const bf16x8*)&Wcomb[(size_t)(ni * 16 + ln16) * 256 + ks * 32 + q * 8];
        #pragma unroll
        for (int mi = 0; mi < 2; mi++)
            #pragma unroll
            for (int ni = 0; ni < 2; ni++)
                acc[mi][ni] = __builtin_amdgcn_mfma_f32_16x16x32_bf16(af[mi], bfrg[ni], acc[mi][ni], 0, 0, 0);
    }

    // ---- in-register softmax + w output + wT tiles + wsum ----
    float bc0 = bcomb[ln16], bc1 = bcomb[16 + ln16];
    float ws0 = 0.0f, ws1 = 0.0f;
    #pragma unroll
    for (int mi = 0; mi < 2; mi++)
        #pragma unroll
        for (int r = 0; r < 4; r++) {
            float l0 = acc[mi][0][r] + bc0;
            float l1 = acc[mi][1][r] + bc1;
            float m = fmaxf(l0, l1);
            #pragma unroll
            for (int msk = 1; msk < 16; msk <<= 1) m = fmaxf(m, __shfl_xor(m, msk, 64));
            float e0 = __expf(l0 - m), e1 = __expf(l1 - m);
            float sum = e0 + e1;
            #pragma unroll
            for (int msk = 1; msk < 16; msk <<= 1) sum += __shfl_xor(sum, msk, 64);
            float is = 1.0f / sum;
            int nl = nl0w + mi * 16 + q * 4 + r;     // local node (row)
            bool valid = nl < NN;
            float w0 = valid ? e0 * is : 0.0f;
            float w1 = valid ? e1 * is : 0.0f;
            u16 h0 = f2bf(w0), h1 = f2bf(w1);
            u16 lo0 = f2bf(w0 - bf2f(h0)), lo1 = f2bf(w1 - bf2f(h1));
            if (valid) {
                size_t gb = ((size_t)b * NN + nl) * SS;
                wout[gb + ln16] = w0;
                wout[gb + 16 + ln16] = w1;
            }
            int nlb = nl - nl0;
            wTh[ln16 * LP_PAD + nlb] = h0;  wTl[ln16 * LP_PAD + nlb] = lo0;
            wTh[(16 + ln16) * LP_PAD + nlb] = h1;  wTl[(16 + ln16) * LP_PAD + nlb] = lo1;
            ws0 += w0;  ws1 += w1;
        }
    // reduce wsum partials across q groups (lanes with same ln16)
    ws0 += __shfl_xor(ws0, 16, 64); ws0 += __shfl_xor(ws0, 32, 64);
    ws1 += __shfl_xor(ws1, 16, 64); ws1 += __shfl_xor(ws1, 32, 64);
    if (q == 0) {
        atomicAdd(&wsum_sh[ln16], ws0);
        atomicAdd(&wsum_sh[16 + ln16], ws1);
    }
    __syncthreads();   // wT/hT writes + wsum_sh atomics complete

    // ---- pooling MFMA: wave wv owns cols [wv*32, wv*32+32); full K sequentially ----
    f32x4 pacc[2][2];
    #pragma unroll
    for (int st = 0; st < 2; st++)
        #pragma unroll
        for (int ctl = 0; ctl < 2; ctl++) pacc[st][ctl] = (f32x4){0.f, 0.f, 0.f, 0.f};
    #pragma unroll
    for (int ks = 0; ks < 4; ks++) {
        int kb = ks * 32 + q * 8;
        bf16x8 wh[2], wl2[2], bfr[2];
        #pragma unroll
        for (int st = 0; st < 2; st++) {
            wh[st] = *(const bf16x8*)&wTh[(st * 16 + ln16) * LP_PAD + kb];
            wl2[st] = *(const bf16x8*)&wTl[(st * 16 + ln16) * LP_PAD + kb];
        }
        #pragma unroll
        for (int ctl = 0; ctl < 2; ctl++)
            bfr[ctl] = *(const bf16x8*)&hT[((wv * 2 + ctl) * 16 + ln16) * LP_PAD + kb];
        #pragma unroll
        for (int ctl = 0; ctl < 2; ctl++)
            #pragma unroll
            for (int st = 0; st < 2; st++) {
                pacc[st][ctl] = __builtin_amdgcn_mfma_f32_16x16x32_bf16(wh[st], bfr[ctl], pacc[st][ctl], 0, 0, 0);
                pacc[st][ctl] = __builtin_amdgcn_mfma_f32_16x16x32_bf16(wl2[st], bfr[ctl], pacc[st][ctl], 0, 0, 0);
            }
    }

    // ---- direct replica atomics (no cross-wave reduce needed) ----
    if (t < SS) atomicAdd(&wsum[b * SS + t], wsum_sh[t]);
    int rep_id = (blockIdx.y * NBLK + blockIdx.x) & (NREP - 1);
    float* dst = rep + ((size_t)rep_id * BATCH + b) * SS * CC;
    #pragma unroll
    for (int st = 0; st < 2; st++)
        #pragma unroll
        for (int ctl = 0; ctl < 2; ctl++)
            #pragma unroll
            for (int r = 0; r < 4; r++)
                atomicAdd(&dst[(st * 16 + q * 4 + r) * CC + (wv * 2 + ctl) * 16 + ln16],
                          pacc[st][ctl][r]);
}

// ---------------- slice MHA, stage 1: qkv = (replica-sum/wsum) @ Win + b_in ----------------
// replica reduction fused in (same r=0..15 summation order as reduce_slices); grid=64.
__global__ __launch_bounds__(128) void qkv_kernel(const float* __restrict__ rep,
                                                  const float* wsum,
                                                  const float* Win, const float* b_in_p,
                                                  float* qkv) {
    int blk = blockIdx.x;  // b*SS + s
    int b = blk >> 5;
    int t = threadIdx.x;
    __shared__ float row[128];
    int e = (blk & 31) * CC + t;          // s*CC + c within batch b
    float s = 0.0f;
    #pragma unroll
    for (int r = 0; r < NREP; r++) s += rep[((size_t)r * BATCH + b) * SS * CC + e];
    float iv = 1.0f / fmaxf(wsum[blk], 1e-8f);
    row[t] = s * iv;
    __syncthreads();
    #pragma unroll
    for (int jj = 0; jj < 3; jj++) {
        int j = t + jj * 128;
        float a = b_in_p[j];
        #pragma unroll 8
        for (int c = 0; c < 128; c++) a += row[c] * Win[c * 384 + j];
        qkv[(size_t)blk * 384 + j] = a;
    }
}

// ---------------- slice MHA, stage 2: attention per (b,h) ----------------
__global__ __launch_bounds__(64) void attn_kernel(const float* qkv, float* ovals) {
    int blk = blockIdx.x;  // b*NH + h
    int b = blk >> 3, h = blk & 7;
    int t = threadIdx.x;
    __shared__ float ksh[32 * 16], vsh[32 * 16];
    for (int i = t; i < 512; i += 64) {
        int k = i >> 4, d = i & 15;
        ksh[i] = qkv[((size_t)b * 32 + k) * 384 + 128 + h * 16 + d];
        vsh[i] = qkv[((size_t)b * 32 + k) * 384 + 256 + h * 16 + d];
    }
    __syncthreads();
    if (t < 32) {
        float qr[16];
        #pragma unroll
        for (int d = 0; d < 16; d++) qr[d] = qkv[((size_t)b * 32 + t) * 384 + h * 16 + d];
        float sc[32];
        float m = -1e30f;
        for (int k = 0; k < 32; k++) {
            float a = 0.0f;
            #pragma unroll
            for (int d = 0; d < 16; d++) a += qr[d] * ksh[k * 16 + d];
            a *= 0.25f;  // 1/sqrt(16)
            sc[k] = a;
            m = fmaxf(m, a);
        }
        float ssum = 0.0f;
        for (int k = 0; k < 32; k++) { float e = expf(sc[k] - m); sc[k] = e; ssum += e; }
        float is = 1.0f / ssum;
        float o[16];
        #pragma unroll
        for (int d = 0; d < 16; d++) o[d] = 0.0f;
        for (int k = 0; k < 32; k++) {
            float p = sc[k] * is;
            #pragma unroll
            for (int d = 0; d < 16; d++) o[d] += p * vsh[k * 16 + d];
        }
        #pragma unroll
        for (int d = 0; d < 16; d++) ovals[((size_t)b * 32 + t) * 128 + h * 16 + d] = o[d];
    }
}

// ---------------- slice MHA, stage 3: soT hi/lo = (o @ Wout + bout)^T, split bf16 ----------------
__global__ __launch_bounds__(128) void mha_out_kernel(const float* ovals, const float* Wout,
                                                      const float* bout,
                                                      u16* soThi, u16* soTlo) {
    int blk = blockIdx.x;  // b*SS + s
    int b = blk >> 5, s = blk & 31;
    int t = threadIdx.x;   // = output col c
    __shared__ float row[128];
    row[t] = ovals[(size_t)blk * 128 + t];
    __syncthreads();
    float a = bout[t];
    #pragma unroll 8
    for (int cc = 0; cc < 128; cc++) a += row[cc] * Wout[cc * CC + t];
    u16 hi = f2bf(a);
    size_t idx = (size_t)b * CC * SS + (size_t)t * SS + s;
    soThi[idx] = hi;
    soTlo[idx] = f2bf(a - bf2f(hi));
}

// ---------------- pack FFN weights to bf16 fragment-friendly layouts ----------------
__global__ __launch_bounds__(256) void pack_ffn_weights(const float* Wff1, const float* Wff2,
                                                        u16* W1p, u16* W2p) {
    int idx = blockIdx.x * 256 + threadIdx.x;
    if (idx >= NL * FFN * CC) return;
    int l = idx / (FFN * CC);
    int r = idx - l * (FFN * CC);
    int j = r >> 7, c = r & 127;          // W1p flat index [l][j][c]
    W1p[idx] = f2bf(Wff1[(size_t)l * CC * FFN + (size_t)c * FFN + j]);
    int c2 = r >> 9, j2 = r & 511;        // W2p flat index [l][c2][j2]
    W2p[idx] = f2bf(Wff2[(size_t)l * FFN * CC + (size_t)j2 * CC + c2]);
}

// ---------------- mega kernel: broadcast + residual + LN2 + FFN + next-layer LN1 ----------------
// R4 structure (verified 148.5 us), FROZEN except phase 0's w source: loads fp32 wout
// (same 32 B/fragment as the old whi+wlo pair) and recomputes hi=f2bf(w),
// lo=f2bf(w-bf2f(hi)) in registers — bit-identical MFMA inputs.
__global__ __launch_bounds__(256, 2) void ffn_mega(float* __restrict__ x,
                                                   const float* __restrict__ wfull,
                                                   const u16* __restrict__ soThi,
                                                   const u16* __restrict__ soTlo,
                                                   const float* __restrict__ g,
                                                   const float* __restrict__ bb,
                                                   const u16* __restrict__ W1p,
                                                   const float* __restrict__ bff1,
                                                   const u16* __restrict__ W2p,
                                                   const float* __restrict__ bff2,
                                                   const float* __restrict__ g1,
                                                   const float* __restrict__ b1,
                                                   u16* __restrict__ hbf_out) {
    __shared__ __align__(16) u16 smem[128 * 144];   // 36864 B: h2t(s136) -> hid dbuf(2x s72) -> stage(s136)
    __shared__ __align__(16) float rowst[128 * 4];  // 2048 B LN stats
    u16* h2t = smem;
    int t = threadIdx.x;
    int b = blockIdx.y;
    int n0 = blockIdx.x * 128;
    int wave = t >> 6, lane = t & 63;
    int wm = wave >> 1, wn = wave & 1;
    int q = lane >> 4, ln16 = lane & 15;
    bool emit = (g1 != nullptr);

    // per-thread LN2 params (cols fixed per thread)
    float gr[4], br[4];
    #pragma unroll
    for (int ni = 0; ni < 4; ni++) {
        int col = wn * 64 + ni * 16 + ln16;
        gr[ni] = g[col]; br[ni] = bb[col];
    }

    f32x4 acc2[4][4];
    #pragma unroll
    for (int mi = 0; mi < 4; mi++)
        #pragma unroll
        for (int ni = 0; ni < 4; ni++) acc2[mi][ni] = (f32x4){0.f, 0.f, 0.f, 0.f};

    // ---- phase 0: acc2 = w@so via 3-pass hi/lo MFMA (hi/lo recomputed from fp32 w) ----
    {
        const u16* soh = soThi + (size_t)b * CC * SS;
        const u16* sol = soTlo + (size_t)b * CC * SS;
        bf16x8 bh[4], bl[4], ah[4], al[4];
        bf16x8 zf;
        #pragma unroll
        for (int i = 0; i < 8; i++) zf[i] = (__bf16)0.0f;
        #pragma unroll
        for (int ni = 0; ni < 4; ni++) {
            int c = wn * 64 + ni * 16 + ln16;
            bh[ni] = *(const bf16x8*)&soh[c * SS + q * 8];
            bl[ni] = *(const bf16x8*)&sol[c * SS + q * 8];
        }
        #pragma unroll
        for (int mi = 0; mi < 4; mi++) {
            int row = n0 + wm * 64 + mi * 16 + ln16;
            if (row < NN) {
                const float* wp = &wfull[((size_t)b * NN + row) * SS + q * 8];
                f32x4 wv0 = *(const f32x4*)wp;
                f32x4 wv1 = *(const f32x4*)(wp + 4);
                union { bf16x8 v; u16 u[8]; } uh, ul;
                #pragma unroll
                for (int i = 0; i < 4; i++) {
                    u16 h = f2bf(wv0[i]);
                    uh.u[i] = h;  ul.u[i] = f2bf(wv0[i] - bf2f(h));
                }
                #pragma unroll
                for (int i = 0; i < 4; i++) {
                    u16 h = f2bf(wv1[i]);
                    uh.u[4 + i] = h;  ul.u[4 + i] = f2bf(wv1[i] - bf2f(h));
                }
                ah[mi] = uh.v;  al[mi] = ul.v;
            } else { ah[mi] = zf; al[mi] = zf; }
        }
        #pragma unroll
        for (int mi = 0; mi < 4; mi++)
            #pragma unroll
            for (int ni = 0; ni < 4; ni++) {
                acc2[mi][ni] = __builtin_amdgcn_mfma_f32_16x16x32_bf16(ah[mi], bh[ni], acc2[mi][ni], 0, 0, 0);
                acc2[mi][ni] = __builtin_amdgcn_mfma_f32_16x16x32_bf16(al[mi], bh[ni], acc2[mi][ni], 0, 0, 0);
                acc2[mi][ni] = __builtin_amdgcn_mfma_f32_16x16x32_bf16(ah[mi], bl[ni], acc2[mi][ni], 0, 0, 0);
            }
    }

    // ---- phase 1: acc2 += x (residual); LN2 stats; h2 -> LDS (stride H2S) ----
    #pragma unroll
    for (int mi = 0; mi < 4; mi++)
        #pragma unroll
        for (int r = 0; r < 4; r++) {
            int row = n0 + wm * 64 + mi * 16 + q * 4 + r;
            if (row < NN) {
                const float* xr = &x[((size_t)b * NN + row) * CC + wn * 64 + ln16];
                #pragma unroll
                for (int ni = 0; ni < 4; ni++) acc2[mi][ni][r] += xr[ni * 16];
            }
        }
    #pragma unroll
    for (int mi = 0; mi < 4; mi++)
        #pragma unroll
        for (int r = 0; r < 4; r++) {
            float a = acc2[mi][0][r] + acc2[mi][1][r] + acc2[mi][2][r] + acc2[mi][3][r];
            float a2 = acc2[mi][0][r] * acc2[mi][0][r] + acc2[mi][1][r] * acc2[mi][1][r] +
                       acc2[mi][2][r] * acc2[mi][2][r] + acc2[mi][3][r] * acc2[mi][3][r];
            #pragma unroll
            for (int msk = 1; msk < 16; msk <<= 1) {
                a += __shfl_xor(a, msk, 64);
                a2 += __shfl_xor(a2, msk, 64);
            }
            if (ln16 == 0) {
                int m = wm * 64 + mi * 16 + q * 4 + r;
                rowst[m * 4 + wn * 2] = a;
                rowst[m * 4 + wn * 2 + 1] = a2;
            }
        }
    __syncthreads();
    #pragma unroll
    for (int mi = 0; mi < 4; mi++)
        #pragma unroll
        for (int r = 0; r < 4; r++) {
            int m = wm * 64 + mi * 16 + q * 4 + r;
            float s1 = rowst[m * 4 + 0] + rowst[m * 4 + 2];
            float s2 = rowst[m * 4 + 1] + rowst[m * 4 + 3];
            float mean = s1 * (1.0f / 128.0f);
            float var = s2 * (1.0f / 128.0f) - mean * mean;
            float rstd = rsqrtf(fmaxf(var, 0.0f) + 1e-5f);
            #pragma unroll
            for (int ni = 0; ni < 4; ni++) {
                int col = wn * 64 + ni * 16 + ln16;
                h2t[m * H2S + col] = f2bf((acc2[mi][ni][r] - mean) * rstd * gr[ni] + br[ni]);
            }
        }
    __syncthreads();

    // ---- phase 1.5: pull this wave's GEMM1 A-fragments into registers (frees smem) ----
    bf16x8 areg[4][4];   // [ks][mi]
    #pragma unroll
    for (int ks = 0; ks < 4; ks++)
        #pragma unroll
        for (int mi = 0; mi < 4; mi++)
            areg[ks][mi] = *(const bf16x8*)&h2t[(wm * 64 + mi * 16 + ln16) * H2S + ks * 32 + q * 8];
    __syncthreads();   // all h2t reads done; smem becomes hid double-buffer

    // ---- phase 2: FFN; ONE barrier per jc; acc2 (holding x+broadcast) accumulates GEMM2 ----
    for (int jc = 0; jc < 8; jc++) {
        u16* hid = smem + (jc & 1) * (128 * HIDS);
        f32x4 acc1[4][2];
        #pragma unroll
        for (int mi = 0; mi < 4; mi++)
            #pragma unroll
            for (int ni = 0; ni < 2; ni++) acc1[mi][ni] = (f32x4){0.f, 0.f, 0.f, 0.f};

        __builtin_amdgcn_s_setprio(1);
        #pragma unroll
        for (int ks = 0; ks < 4; ks++) {
            bf16x8 bfr[2];
            #pragma unroll
            for (int ni = 0; ni < 2; ni++)
                bfr[ni] = *(const bf16x8*)&W1p[(size_t)(jc * 64 + wn * 32 + ni * 16 + ln16) * CC + ks * 32 + q * 8];
            #pragma unroll
            for (int mi = 0; mi < 4; mi++)
                #pragma unroll
                for (int ni = 0; ni < 2; ni++)
                    acc1[mi][ni] = __builtin_amdgcn_mfma_f32_16x16x32_bf16(areg[ks][mi], bfr[ni], acc1[mi][ni], 0, 0, 0);
        }
        __builtin_amdgcn_s_setprio(0);

        #pragma unroll
        for (int ni = 0; ni < 2; ni++) {
            float b1v = bff1[jc * 64 + wn * 32 + ni * 16 + ln16];
            #pragma unroll
            for (int mi = 0; mi < 4; mi++)
                #pragma unroll
                for (int r = 0; r < 4; r++)
                    hid[(wm * 64 + mi * 16 + q * 4 + r) * HIDS + wn * 32 + ni * 16 + ln16] =
                        f2bf(gelu_f(acc1[mi][ni][r] + b1v));
        }
        __syncthreads();   // hid[jc&1] complete; next jc writes the other buffer

        __builtin_amdgcn_s_setprio(1);
        #pragma unroll
        for (int ks2 = 0; ks2 < 2; ks2++) {
            bf16x8 af[4], bfr[4];
            #pragma unroll
            for (int mi = 0; mi < 4; mi++)
                af[mi] = *(const bf16x8*)&hid[(wm * 64 + mi * 16 + ln16) * HIDS + ks2 * 32 + q * 8];
            #pragma unroll
            for (int ni = 0; ni < 4; ni++)
                bfr[ni] = *(const bf16x8*)&W2p[(size_t)(wn * 64 + ni * 16 + ln16) * FFN + jc * 64 + ks2 * 32 + q * 8];
            #pragma unroll
            for (int mi = 0; mi < 4; mi++)
                #pragma unroll
                for (int ni = 0; ni < 4; ni++)
                    acc2[mi][ni] = __builtin_amdgcn_mfma_f32_16x16x32_bf16(af[mi], bfr[ni], acc2[mi][ni], 0, 0, 0);
        }
        __builtin_amdgcn_s_setprio(0);
    }

    // ---- epilogue: fold bff2; store x; optional next-layer LN1 -> hbf (staged, coalesced) ----
    float b2[4];
    #pragma unroll
    for (int ni = 0; ni < 4; ni++) b2[ni] = bff2[wn * 64 + ni * 16 + ln16];
    #pragma unroll
    for (int mi = 0; mi < 4; mi++)
        #pragma unroll
        for (int ni = 0; ni < 4; ni++)
            #pragma unroll
            for (int r = 0; r < 4; r++) acc2[mi][ni][r] += b2[ni];

    #pragma unroll
    for (int mi = 0; mi < 4; mi++)
        #pragma unroll
        for (int r = 0; r < 4; r++) {
            int row = n0 + wm * 64 + mi * 16 + q * 4 + r;
            if (row < NN) {
                float* xo = &x[((size_t)b * NN + row) * CC + wn * 64 + ln16];
                #pragma unroll
                for (int ni = 0; ni < 4; ni++) xo[ni * 16] = acc2[mi][ni][r];
            }
        }

    if (emit) {
        float g1r[4], b1r[4];
        #pragma unroll
        for (int ni = 0; ni < 4; ni++) {
            int col = wn * 64 + ni * 16 + ln16;
            g1r[ni] = g1[col]; b1r[ni] = b1[col];
        }
        #pragma unroll
        for (int mi = 0; mi < 4; mi++)
            #pragma unroll
            for (int r = 0; r < 4; r++) {
                float a = acc2[mi][0][r] + acc2[mi][1][r] + acc2[mi][2][r] + acc2[mi][3][r];
                float a2 = acc2[mi][0][r] * acc2[mi][0][r] + acc2[mi][1][r] * acc2[mi][1][r] +
                           acc2[mi][2][r] * acc2[mi][2][r] + acc2[mi][3][r] * acc2[mi][3][r];
                #pragma unroll
                for (int msk = 1; msk < 16; msk <<= 1) {
                    a += __shfl_xor(a, msk, 64);
                    a2 += __shfl_xor(a2, msk, 64);
                }
                if (ln16 == 0) {
                    int m = wm * 64 + mi * 16 + q * 4 + r;
                    rowst[m * 4 + wn * 2] = a;
                    rowst[m * 4 + wn * 2 + 1] = a2;
                }
            }
        __syncthreads();   // rowst visible AND all jc-loop hid reads drained -> smem reusable
        #pragma unroll
        for (int mi = 0; mi < 4; mi++)
            #pragma unroll
            for (int r = 0; r < 4; r++) {
                int m = wm * 64 + mi * 16 + q * 4 + r;
                float s1 = rowst[m * 4 + 0] + rowst[m * 4 + 2];
                float s2 = rowst[m * 4 + 1] + rowst[m * 4 + 3];
                float mean = s1 * (1.0f / 128.0f);
                float var = s2 * (1.0f / 128.0f) - mean * mean;
                float rstd = rsqrtf(fmaxf(var, 0.0f) + 1e-5f);
                #pragma unroll
                for (int ni = 0; ni < 4; ni++) {
                    int col = wn * 64 + ni * 16 + ln16;
                    smem[m * H2S + col] = f2bf((acc2[mi][ni][r] - mean) * rstd * g1r[ni] + b1r[ni]);
                }
            }
        __syncthreads();
        // coalesced 16B-chunk copy LDS -> hbf_out
        #pragma unroll
        for (int it = 0; it < 8; it++) {
            int chunk = it * 256 + t;            // 2048 chunks = 128 rows x 16 chunks
            int m = chunk >> 4;
            int c8 = (chunk & 15) << 3;
            int row = n0 + m;
            if (row < NN)
                *(f32x4*)&hbf_out[((size_t)b * NN + row) * CC + c8] =
                    *(const f32x4*)&smem[m * H2S + c8];
        }
    }
}

// ---------------- final projection ----------------
__global__ __launch_bounds__(128) void proj_kernel(const float* __restrict__ x,
                                                   const float* __restrict__ W,
                                                   const float* __restrict__ bias,
                                                   float* __restrict__ outp) {
    int t = threadIdx.x;
    int n0 = blockIdx.x * PROJ_NPB;
    __shared__ float xr[PROJ_NPB][128];
    __shared__ float pr[3][40];
    for (int idx = t; idx < PROJ_NPB * 128; idx += 128) {
        int nn = idx >> 7, c = idx & 127;
        int node = n0 + nn;
        xr[nn][c] = (node < NTOT) ? x[(size_t)node * CC + c] : 0.0f;
    }
    __syncthreads();
    for (int pass = 0; pass < 4; pass++) {
        if (t < 120) {
            int nl = t / 40, tt = t - nl * 40;
            int k = tt / 8, part = tt % 8;
            float a = 0.0f;
            #pragma unroll
            for (int i = 0; i < 16; i++) {
                int c = part * 16 + i;
                a += xr[pass * 3 + nl][c] * W[c * C_IN + k];
            }
            pr[nl][tt] = a;
        }
        __syncthreads();
        if (t < 15) {
            int nl = t / 5, k = t - nl * 5;
            int node = n0 + pass * 3 + nl;
            if (node < NTOT) {
                float a = bias[k];
                #pragma unroll
                for (int p = 0; p < 8; p++) a += pr[nl][k * 8 + p];
                outp[(size_t)node * C_IN + k] = a;
            }
        }
        __syncthreads();
    }
}

extern "C" void kernel_launch(void* const* d_in, const int* in_sizes, int n_in,
                              void* d_out, int out_size, void* d_ws, size_t ws_size,
                              hipStream_t stream) {
    const float* inputs  = (const float*)d_in[0];
    const float* coords  = (const float*)d_in[1];
    const float* t_norm  = (const float*)d_in[2];
    const int*   adj     = (const int*)d_in[3];
    const float* adj_v   = (const float*)d_in[4];
    const float* freq    = (const float*)d_in[5];
    const float* embed_W = (const float*)d_in[6];
    const float* embed_b = (const float*)d_in[7];
    const float* ln1_g   = (const float*)d_in[8];
    const float* ln1_b   = (const float*)d_in[9];
    const float* Wslice  = (const float*)d_in[10];
    const float* bslice  = (const float*)d_in[11];
    const float* Wfront  = (const float*)d_in[12];
    const float* bfront  = (const float*)d_in[13];
    const float* Win     = (const float*)d_in[14];
    const float* b_in    = (const float*)d_in[15];
    const float* Wout    = (const float*)d_in[16];
    const float* bout    = (const float*)d_in[17];
    const float* ln2_g   = (const float*)d_in[18];
    const float* ln2_b   = (const float*)d_in[19];
    const float* Wff1    = (const float*)d_in[20];
    const float* bff1    = (const float*)d_in[21];
    const float* Wff2    = (const float*)d_in[22];
    const float* bff2    = (const float*)d_in[23];
    const float* proj_W  = (const float*)d_in[24];
    const float* proj_b  = (const float*)d_in[25];

    float* out = (float*)d_out;
    float* wout_base = out + (size_t)BATCH * NN * C_IN;

    // workspace layout
    float* x          = (float*)d_ws;
    u16*   hbf        = (u16*)(x + (size_t)NTOT * CC);
    u16*   hlbf       = hbf + (size_t)MPAD * CC;
    u16*   soThi      = hlbf + (size_t)MPAD * CC;            // BATCH*CC*SS
    u16*   soTlo      = soThi + BATCH * CC * SS;
    float* qkv_ws     = (float*)(soTlo + BATCH * CC * SS);   // BATCH*SS*384
    float* ovals_ws   = qkv_ws + BATCH * SS * 384;           // BATCH*SS*CC
    float* csr_val    = ovals_ws + BATCH * SS * CC;
    int*   rowptr     = (int*)(csr_val + NE);
    int*   cursor     = rowptr + (NN + 1);
    int*   deg        = cursor + NN;
    int*   csr_col    = deg + NN;
    u16*   W1p        = (u16*)(csr_col + NE);       // NL*FFN*CC bf16
    u16*   W2p        = W1p + NL * FFN * CC;        // NL*CC*FFN bf16
    u16*   Wcombp     = W2p + NL * CC * FFN;        // NL*SS*256 bf16
    float* bcomb      = (float*)(Wcombp + NL * SS * 256);  // NL*SS fp32
    float* rep        = bcomb + NL * SS;            // NREP*BATCH*SS*CC fp32 (512 KB)
    float* wsum       = rep + (size_t)NREP * BATCH * SS * CC;  // BATCH*SS, adjacent for 1 memset

    // ---- CSR build ----
    hipMemsetAsync(deg, 0, NN * sizeof(int), stream);
    count_deg<<<(NE + 255) / 256, 256, 0, stream>>>(adj, deg);
    scan_deg<<<1, 512, 0, stream>>>(deg, rowptr);
    hipMemcpyAsync(cursor, rowptr, NN * sizeof(int), hipMemcpyDeviceToDevice, stream);
    fill_csr<<<(NE + 255) / 256, 256, 0, stream>>>(adj, adj + NE, adj_v, cursor, csr_col, csr_val);

    // ---- pack weights (bf16) ----
    pack_ffn_weights<<<(NL * FFN * CC + 255) / 256, 256, 0, stream>>>(Wff1, Wff2, W1p, W2p);
    pack_logits_weights<<<(NL * SS * 256 + 255) / 256, 256, 0, stream>>>(Wslice, bslice, Wfront,
                                                                         bfront, Wcombp, bcomb);

    // ---- embed + LN1(layer 0) ----
    embed_ln1_kernel<<<(NTOT + EMB_NPB - 1) / EMB_NPB, 128, 0, stream>>>(
        inputs, coords, t_norm, freq, embed_W, embed_b, ln1_g, ln1_b, x, hbf);

    for (int l = 0; l < NL; l++) {
        float* wl = wout_base + (size_t)l * NTOT * SS;
        agg_kernel<<<NTOT / 4, 256, 0, stream>>>(hbf, rowptr, csr_col, csr_val, hlbf);
        hipMemsetAsync(rep, 0, ((size_t)NREP * BATCH * SS * CC + BATCH * SS) * sizeof(float), stream);
        dim3 glp(NBLK, BATCH);
        logits_pool<<<glp, 256, 0, stream>>>(hbf, hlbf, Wcombp + (size_t)l * SS * 256,
                                             bcomb + l * SS, wl, rep, wsum);
        // MHA (3-stage; replica reduce fused into qkv; grid 64/16/64)
        qkv_kernel<<<BATCH * SS, 128, 0, stream>>>(rep, wsum,
                                                   Win + (size_t)l * CC * 3 * CC,
                                                   b_in + l * 3 * CC, qkv_ws);
        attn_kernel<<<BATCH * NH, 64, 0, stream>>>(qkv_ws, ovals_ws);
        mha_out_kernel<<<BATCH * SS, 128, 0, stream>>>(ovals_ws, Wout + (size_t)l * CC * CC,
                                                       bout + l * CC, soThi, soTlo);
        // fused broadcast + LN2 + FFN + next-layer LN1 (R4 structure; w from wout fp32)
        const float* g1n = (l + 1 < NL) ? (ln1_g + (size_t)(l + 1) * CC) : nullptr;
        const float* b1n = (l + 1 < NL) ? (ln1_b + (size_t)(l + 1) * CC) : nullptr;
        dim3 g3(NBLK, BATCH);
        ffn_mega<<<g3, 256, 0, stream>>>(x, wl, soThi, soTlo,
                                         ln2_g + l * CC, ln2_b + l * CC,
                                         W1p + (size_t)l * FFN * CC, bff1 + l * FFN,
                                         W2p + (size_t)l * CC * FFN, bff2 + l * CC,
                                         g1n, b1n, hbf);
    }

    proj_kernel<<<(NTOT + PROJ_NPB - 1) / PROJ_NPB, 128, 0, stream>>>(x, proj_W, proj_b, out);
}